// Round 5
// baseline (185.903 us; speedup 1.0000x reference)
//
#include <hip/hip_runtime.h>
#include <math.h>

// Problem constants
#define B_   64
#define T_   512
#define D_   96
#define TY_  512
#define H_   4
#define DK_  32
#define E_   128
#define P_   2
#define L_   64
#define HID_ 128

// Workspace layout (float offsets)
#define WS_OB2P  1024      // 8*64 : ob2 partials (const-half of ow, 8 slices)
#define WS_PN    2048      // 64b*8c*8hp*96f = 393216 : partial numerators
#define WS_PD    395264    // 393216 : partial denominators

// ---------------------------------------------------------------------------
// Kernel 1 (512 blocks = 8 t-chunks x 64 b, 256 thr): prep + scores + exp +
// masked pooling partials. (unchanged from round 4 — ~17 us, latency-bound)
// ---------------------------------------------------------------------------
__global__ __launch_bounds__(256) void kphase1(
    const float* __restrict__ tsteps, const float* __restrict__ te_w,
    const float* __restrict__ te_b,   const float* __restrict__ X,
    const float* __restrict__ M,      const float* __restrict__ query,
    const float* __restrict__ q_w,    const float* __restrict__ q_b,
    const float* __restrict__ k_w,    const float* __restrict__ k_b,
    const float* __restrict__ ow,     float* __restrict__ ws)
{
    const int bi = blockIdx.x, tid = threadIdx.x;
    const int c = bi & 7, b = bi >> 3;

    __shared__ float qm[P_ * E_];
    __shared__ float w2q_s[E_ * 8];
    __shared__ float tw_s[E_], tb_s[E_], bq_s[8];
    __shared__ float w_sB[64][8];       // [t][hp]
    __shared__ float red[96 * 17];      // stride 17: no bank conflicts
    __shared__ float obp2[4][64];

    // ---- Prologue: fused q/k weights ----
    {
        int p = tid >> 7, ep = tid & 127;
        float acc = q_b[ep];
        #pragma unroll 8
        for (int e = 0; e < E_; ++e)
            acc += query[p * E_ + e] * q_w[e * E_ + ep];
        qm[p * E_ + ep] = acc;
    }
    if (tid < E_) { tw_s[tid] = te_w[tid]; tb_s[tid] = te_b[tid]; }
    __syncthreads();
    const float rs = 0.17677669529663687f;  // 1/sqrt(32)
    #pragma unroll
    for (int i = 0; i < 4; ++i) {
        int idx = tid + i * 256;
        int e = idx >> 3, hp = idx & 7, h = hp >> 1, p = hp & 1;
        float acc = 0.f;
        #pragma unroll
        for (int dk = 0; dk < DK_; ++dk)
            acc += k_w[e * E_ + h * DK_ + dk] * qm[p * E_ + h * DK_ + dk];
        w2q_s[idx] = acc * rs;
    }
    if (tid < 8) {
        int hp = tid, h = hp >> 1, p = hp & 1;
        float acc = 0.f;
        #pragma unroll
        for (int dk = 0; dk < DK_; ++dk)
            acc += k_b[h * DK_ + dk] * qm[p * E_ + h * DK_ + dk];
        bq_s[hp] = acc * rs;
    }
    __syncthreads();

    // ---- Phase A: thread = (t in chunk, hp-pair) ----
    {
        const int t = tid & 63, hpg = tid >> 6, hp0 = hpg * 2;
        const float tv = tsteps[b * T_ + c * 64 + t];
        float a0 = 0.f, a1 = 0.f;
        #pragma unroll 4
        for (int e = 0; e < E_; ++e) {
            float v = tv * tw_s[e] + tb_s[e];
            if ((e & 3) == 0) v = __sinf(v);
            float2 w = *(const float2*)&w2q_s[e * 8 + hp0];
            a0 += v * w.x;
            a1 += v * w.y;
        }
        float e0 = __expf(a0 + bq_s[hp0]);
        float e1 = __expf(a1 + bq_s[hp0 + 1]);
        *(float2*)&w_sB[t][hp0] = make_float2(e0, e1);
    }
    __syncthreads();

    // ---- Phase B: 2 t-slices x 128 fid (96 active) ----
    const int fid = tid & 127, slice = tid >> 7;
    float num[8] = {0.f, 0.f, 0.f, 0.f, 0.f, 0.f, 0.f, 0.f};
    float den[8] = {0.f, 0.f, 0.f, 0.f, 0.f, 0.f, 0.f, 0.f};
    if (fid < 96) {
        #pragma unroll 4
        for (int i = 0; i < 32; ++i) {
            int tl = slice + 2 * i;           // wave-uniform
            size_t base = ((size_t)(b * T_ + c * 64 + tl)) * D_ + fid;
            float m = M[base], x = X[base];
            float mx = m * x;
            float4 wa = *(const float4*)&w_sB[tl][0];   // b128 broadcast
            float4 wb = *(const float4*)&w_sB[tl][4];
            float wv[8];
            *(float4*)&wv[0] = wa; *(float4*)&wv[4] = wb;
            #pragma unroll
            for (int hp = 0; hp < 8; ++hp) {
                num[hp] += wv[hp] * mx;
                den[hp] += wv[hp] * m;
            }
        }
    }
    __syncthreads();
    if (slice == 1 && fid < 96) {
        #pragma unroll
        for (int hp = 0; hp < 8; ++hp) {
            red[fid * 17 + hp]     = num[hp];
            red[fid * 17 + 8 + hp] = den[hp];
        }
    }
    __syncthreads();
    if (slice == 0 && fid < 96) {
        float* pN = ws + WS_PN + ((size_t)((b * 8 + c) * 8)) * 96;
        float* pD = ws + WS_PD + ((size_t)((b * 8 + c) * 8)) * 96;
        #pragma unroll
        for (int hp = 0; hp < 8; ++hp) {
            pN[hp * 96 + fid] = num[hp] + red[fid * 17 + hp];
            pD[hp * 96 + fid] = den[hp] + red[fid * 17 + 8 + hp];
        }
    }

    // ---- Epilogue (b==0 only): ob2 partial slice c over 48 (h,j) pairs ----
    if (b == 0) {
        int sub = tid >> 6, l = tid & 63;
        float acc = 0.f;
        #pragma unroll
        for (int k = 0; k < 12; ++k) {
            int hj = c * 48 + sub * 12 + k;
            int h = hj / 96, j = hj - h * 96;
            acc += ow[(size_t)(h * 2 * D_ + D_ + j) * L_ + l];
        }
        obp2[sub][l] = acc;
        __syncthreads();
        if (sub == 0)
            ws[WS_OB2P + c * 64 + l] = obp2[0][l] + obp2[1][l]
                                     + obp2[2][l] + obp2[3][l];
    }
}

// ---------------------------------------------------------------------------
// Kernel SWEEP (64 blocks x 512 thr, one per b): partials -> xa -> coeffs ->
// (a0,a1) -> piecewise-linear sweep -> out. No tables in global, no 3rd
// kernel (round-5 change: kdec's 25 MB cross-XCD table reads + one launch
// gap removed).
//
// out[pos,d] = sum_j relu(a0_j + y*a1_j) w2[j,d] + b2[d] is piecewise-linear
// in y. relu(x) = (x+|x|)/2, |a0+y*a1| = |a1|*|y-t_j|, t_j = -a0/a1,
// u_j = |a1_j|, vt_j = -a0_j*sgn(a1_j):
//   out(y) = R0(k) + y*R1(k), k = #{t_j < y}
//   R0(0) = 0.5*(G0 + C + Vtot) + b2 ; R1(0) = 0.5*(G1 - Utot)
//   crossing t_(k): R0 -= vt*w2row ; R1 += u*w2row
// Sweep: sort y's (rank sort, tiebreak by index), walk thresholds in sorted
// order keeping (R0,R1) per column d in 2 registers; emit out rows in y
// order (same update summation order as round 4 -> identical numerics).
// 4 y-segments x 128 sorted y's; each segment = 2 waves (dd<96 active),
// wave-uniform control flow.
// ---------------------------------------------------------------------------
__global__ __launch_bounds__(512) void ksweep(
    const float* __restrict__ ow, const float* __restrict__ ob,
    const float* __restrict__ w1, const float* __restrict__ b1,
    const float* __restrict__ yts, const float* __restrict__ w2,
    const float* __restrict__ b2, const float* __restrict__ ws,
    float* __restrict__ out)
{
    __shared__ float w2_s[HID_ * D_];   // 48 KB, [j][d]
    union Scr {
        struct { float xa[768]; float cfp[4][2][64]; float abp[2][2][128]; } e;
        struct { float ysv[512]; int ysi[512]; float ts[128]; } l;
    };
    __shared__ Scr scr;                 // 7 KB, early/late overlay
    __shared__ float yload_s[512];
    __shared__ float cf_s[2][64];
    __shared__ float ab0_s[HID_], ab1_s[HID_];
    __shared__ float t_s[HID_], u_s[HID_], vt_s[HID_], c0_s[HID_];
    __shared__ int   sidx_s[HID_];
    __shared__ float base0_s[96], base1_s[96];
    // total static LDS ~62 KB

    const int b = blockIdx.x, tid = threadIdx.x;

    // stage w2 (12288 floats, 6 float4/thread, coalesced) + y values
    {
        const float4* src = (const float4*)w2;
        float4* dst = (float4*)w2_s;
        #pragma unroll
        for (int i = 0; i < 6; ++i) dst[tid + i * 512] = src[tid + i * 512];
    }
    yload_s[tid] = yts[b * TY_ + tid];

    // (a) reduce pool partials -> xa (768 items / 512 threads)
    for (int flat = tid; flat < 8 * 96; flat += 512) {
        int hp = flat / 96, f = flat - hp * 96;
        float n = 0.f, d = 0.f;
        #pragma unroll
        for (int cc = 0; cc < 8; ++cc) {
            n += ws[WS_PN + ((size_t)((b * 8 + cc) * 8 + hp)) * 96 + f];
            d += ws[WS_PD + ((size_t)((b * 8 + cc) * 8 + hp)) * 96 + f];
        }
        scr.e.xa[flat] = n / d;
    }
    __syncthreads();

    // (b) coeff GEMV: 512 items (h,p,l), exactly 1/thread
    {
        int h = tid >> 7, p = (tid >> 6) & 1, l = tid & 63;
        const float* xr = scr.e.xa + (h * 2 + p) * 96;
        const float* owr = ow + (size_t)(h * 2 * D_) * L_ + l;
        float acc = 0.f;
        #pragma unroll 8
        for (int f = 0; f < 96; ++f)
            acc += xr[f] * owr[(size_t)f * L_];
        scr.e.cfp[h][p][l] = acc;
    }
    __syncthreads();

    // (c) combine coeff partials + ob + ob2 partials
    if (tid < 128) {
        int p = tid >> 6, l = tid & 63;
        float v = scr.e.cfp[0][p][l] + scr.e.cfp[1][p][l] + scr.e.cfp[2][p][l]
                + scr.e.cfp[3][p][l] + ob[l];
        #pragma unroll
        for (int g = 0; g < 8; ++g) v += ws[WS_OB2P + g * 64 + l];
        cf_s[p][l] = v;
    }
    __syncthreads();

    // (d) a0/a1 GEMV, 256 items (s,j)
    if (tid < 256) {
        int s = tid >> 7, j = tid & 127;
        float a0 = 0.f, a1 = 0.f;
        #pragma unroll 4
        for (int li = 0; li < 32; ++li) {
            int l = s * 32 + li;
            float wv = w1[l * HID_ + j];
            a0 += cf_s[0][l] * wv;
            a1 += cf_s[1][l] * wv;
        }
        scr.e.abp[s][0][j] = a0;
        scr.e.abp[s][1][j] = a1;
    }
    __syncthreads();

    // (e) combine -> ab0/ab1 (last reader of union.early)
    if (tid < 128) {
        ab0_s[tid] = scr.e.abp[0][0][tid] + scr.e.abp[1][0][tid] + b1[tid];
    } else if (tid < 256) {
        int j = tid - 128;
        ab1_s[j] = scr.e.abp[0][1][j] + scr.e.abp[1][1][j];
    }
    __syncthreads();

    // (f) classify [tid<128] ; y rank-sort [all threads -> union.late]
    if (tid < 128) {
        float a0 = ab0_s[tid], a1 = ab1_s[tid];
        float t, u, vt, c0;
        if (a1 > 0.f)      { t = -a0 / a1;  u =  a1; vt = -a0; c0 = 0.f; }
        else if (a1 < 0.f) { t = -a0 / a1;  u = -a1; vt =  a0; c0 = 0.f; }
        else               { t = INFINITY;  u = 0.f; vt = 0.f; c0 = fabsf(a0); }
        t_s[tid] = t; u_s[tid] = u; vt_s[tid] = vt; c0_s[tid] = c0;
    }
    {
        float y = yload_s[tid];
        int r = 0;
        #pragma unroll 8
        for (int k = 0; k < 512; ++k) {
            float yk = yload_s[k];
            r += (yk < y) || (yk == y && k < tid);
        }
        scr.l.ysv[r] = y;
        scr.l.ysi[r] = tid;
    }
    __syncthreads();

    // (g) threshold rank sort (strict total order via index tiebreak)
    if (tid < 128) {
        float tj = t_s[tid];
        int r = 0;
        #pragma unroll 8
        for (int k = 0; k < 128; ++k) {
            float tk = t_s[k];
            r += (tk < tj) || (tk == tj && k < tid);
        }
        sidx_s[r] = tid;
    }
    __syncthreads();

    // (h) fused 5-GEMV -> base state (k=0); [128,256) writes sorted t
    if (tid < 96) {
        float g0 = 0.f, g1 = 0.f, ut = 0.f, vta = 0.f, cc2 = 0.f;
        #pragma unroll 4
        for (int j = 0; j < 128; ++j) {
            float wv = w2_s[j * 96 + tid];
            g0  += ab0_s[j] * wv;
            g1  += ab1_s[j] * wv;
            ut  += u_s[j]  * wv;
            vta += vt_s[j] * wv;
            cc2 += c0_s[j] * wv;
        }
        base0_s[tid] = 0.5f * (g0 + cc2 + vta) + b2[tid];
        base1_s[tid] = 0.5f * (g1 - ut);
    } else if (tid >= 128 && tid < 256) {
        int k = tid - 128;
        scr.l.ts[k] = t_s[sidx_s[k]];
    }
    __syncthreads();

    // (i) sweep: seg = tid>>7 owns sorted y's [seg*128, seg*128+128);
    // dd = tid&127 (<96 active) owns column dd. Control flow is uniform
    // across each segment's 2 waves. Each segment catches up from k=0
    // (<=128 extra updates — cheap) then interleaves updates and emits.
    {
        const int seg = tid >> 7, dd = tid & 127;
        if (dd < 96) {
            float cur0 = base0_s[dd], cur1 = base1_s[dd];
            int ptr = 0;
            const int i0 = seg * 128, i1 = i0 + 128;
            #pragma unroll 1
            for (int i = i0; i < i1; ++i) {
                float y = scr.l.ysv[i];
                while (ptr < 128 && scr.l.ts[ptr] < y) {
                    int j = sidx_s[ptr];
                    float wv = w2_s[j * 96 + dd];
                    cur0 -= vt_s[j] * wv;
                    cur1 += u_s[j] * wv;
                    ++ptr;
                }
                int pos = scr.l.ysi[i];
                out[((size_t)(b * TY_ + pos)) * D_ + dd] = cur0 + y * cur1;
            }
        }
    }
}

// ---------------------------------------------------------------------------
extern "C" void kernel_launch(void* const* d_in, const int* in_sizes, int n_in,
                              void* d_out, int out_size, void* d_ws, size_t ws_size,
                              hipStream_t stream)
{
    const float* timesteps = (const float*)d_in[0];
    const float* X         = (const float*)d_in[1];
    const float* M         = (const float*)d_in[2];
    const float* yts       = (const float*)d_in[3];
    const float* te_w      = (const float*)d_in[4];
    const float* te_b      = (const float*)d_in[5];
    const float* query     = (const float*)d_in[6];
    const float* q_w       = (const float*)d_in[7];
    const float* q_b       = (const float*)d_in[8];
    const float* k_w       = (const float*)d_in[9];
    const float* k_b       = (const float*)d_in[10];
    const float* ow        = (const float*)d_in[11];
    const float* ob        = (const float*)d_in[12];
    const float* w1        = (const float*)d_in[13];
    const float* b1        = (const float*)d_in[14];
    const float* w2        = (const float*)d_in[15];
    const float* b2        = (const float*)d_in[16];
    float* out = (float*)d_out;
    float* ws  = (float*)d_ws;

    kphase1<<<512, 256, 0, stream>>>(timesteps, te_w, te_b, X, M, query,
                                     q_w, q_b, k_w, k_b, ow, ws);
    ksweep<<<B_, 512, 0, stream>>>(ow, ob, w1, b1, yts, w2, b2, ws, out);
}

// Round 6
// 154.500 us; speedup vs baseline: 1.2033x; 1.2033x over previous
//
#include <hip/hip_runtime.h>
#include <math.h>

// Problem constants
#define B_   64
#define T_   512
#define D_   96
#define TY_  512
#define H_   4
#define DK_  32
#define E_   128
#define P_   2
#define L_   64
#define HID_ 128

// Workspace layout (float offsets)
#define WS_OB2P  1024      // 8*64 : ob2 partials (const-half of ow, 8 slices)
#define WS_PN    2048      // 64b*8c*8hp*96f = 393216 : partial numerators
#define WS_PD    395264    // 393216 : partial denominators

// LDS table row stride (floats): 194 = 192 data + 2 pad.
//   194 mod 32 = 2  -> bank(row k, col c) = (2k + c) mod 32: 32 different k
//   across a wave spread over 16 banks (2-way, free).  194 even -> float2-
//   aligned rows. Row k: R0[96] at [0,96), R1[96] at [96,192).
#define TS_  194

// ---------------------------------------------------------------------------
// Kernel 1 (512 blocks = 8 t-chunks x 64 b, 256 thr): prep + scores + exp +
// masked pooling partials. (unchanged from round 4 — ~16 us)
// ---------------------------------------------------------------------------
__global__ __launch_bounds__(256) void kphase1(
    const float* __restrict__ tsteps, const float* __restrict__ te_w,
    const float* __restrict__ te_b,   const float* __restrict__ X,
    const float* __restrict__ M,      const float* __restrict__ query,
    const float* __restrict__ q_w,    const float* __restrict__ q_b,
    const float* __restrict__ k_w,    const float* __restrict__ k_b,
    const float* __restrict__ ow,     float* __restrict__ ws)
{
    const int bi = blockIdx.x, tid = threadIdx.x;
    const int c = bi & 7, b = bi >> 3;

    __shared__ float qm[P_ * E_];
    __shared__ float w2q_s[E_ * 8];
    __shared__ float tw_s[E_], tb_s[E_], bq_s[8];
    __shared__ float w_sB[64][8];       // [t][hp]
    __shared__ float red[96 * 17];      // stride 17: no bank conflicts
    __shared__ float obp2[4][64];

    // ---- Prologue: fused q/k weights ----
    {
        int p = tid >> 7, ep = tid & 127;
        float acc = q_b[ep];
        #pragma unroll 8
        for (int e = 0; e < E_; ++e)
            acc += query[p * E_ + e] * q_w[e * E_ + ep];
        qm[p * E_ + ep] = acc;
    }
    if (tid < E_) { tw_s[tid] = te_w[tid]; tb_s[tid] = te_b[tid]; }
    __syncthreads();
    const float rs = 0.17677669529663687f;  // 1/sqrt(32)
    #pragma unroll
    for (int i = 0; i < 4; ++i) {
        int idx = tid + i * 256;
        int e = idx >> 3, hp = idx & 7, h = hp >> 1, p = hp & 1;
        float acc = 0.f;
        #pragma unroll
        for (int dk = 0; dk < DK_; ++dk)
            acc += k_w[e * E_ + h * DK_ + dk] * qm[p * E_ + h * DK_ + dk];
        w2q_s[idx] = acc * rs;
    }
    if (tid < 8) {
        int hp = tid, h = hp >> 1, p = hp & 1;
        float acc = 0.f;
        #pragma unroll
        for (int dk = 0; dk < DK_; ++dk)
            acc += k_b[h * DK_ + dk] * qm[p * E_ + h * DK_ + dk];
        bq_s[hp] = acc * rs;
    }
    __syncthreads();

    // ---- Phase A: thread = (t in chunk, hp-pair) ----
    {
        const int t = tid & 63, hpg = tid >> 6, hp0 = hpg * 2;
        const float tv = tsteps[b * T_ + c * 64 + t];
        float a0 = 0.f, a1 = 0.f;
        #pragma unroll 4
        for (int e = 0; e < E_; ++e) {
            float v = tv * tw_s[e] + tb_s[e];
            if ((e & 3) == 0) v = __sinf(v);
            float2 w = *(const float2*)&w2q_s[e * 8 + hp0];
            a0 += v * w.x;
            a1 += v * w.y;
        }
        float e0 = __expf(a0 + bq_s[hp0]);
        float e1 = __expf(a1 + bq_s[hp0 + 1]);
        *(float2*)&w_sB[t][hp0] = make_float2(e0, e1);
    }
    __syncthreads();

    // ---- Phase B: 2 t-slices x 128 fid (96 active) ----
    const int fid = tid & 127, slice = tid >> 7;
    float num[8] = {0.f, 0.f, 0.f, 0.f, 0.f, 0.f, 0.f, 0.f};
    float den[8] = {0.f, 0.f, 0.f, 0.f, 0.f, 0.f, 0.f, 0.f};
    if (fid < 96) {
        #pragma unroll 4
        for (int i = 0; i < 32; ++i) {
            int tl = slice + 2 * i;           // wave-uniform
            size_t base = ((size_t)(b * T_ + c * 64 + tl)) * D_ + fid;
            float m = M[base], x = X[base];
            float mx = m * x;
            float4 wa = *(const float4*)&w_sB[tl][0];   // b128 broadcast
            float4 wb = *(const float4*)&w_sB[tl][4];
            float wv[8];
            *(float4*)&wv[0] = wa; *(float4*)&wv[4] = wb;
            #pragma unroll
            for (int hp = 0; hp < 8; ++hp) {
                num[hp] += wv[hp] * mx;
                den[hp] += wv[hp] * m;
            }
        }
    }
    __syncthreads();
    if (slice == 1 && fid < 96) {
        #pragma unroll
        for (int hp = 0; hp < 8; ++hp) {
            red[fid * 17 + hp]     = num[hp];
            red[fid * 17 + 8 + hp] = den[hp];
        }
    }
    __syncthreads();
    if (slice == 0 && fid < 96) {
        float* pN = ws + WS_PN + ((size_t)((b * 8 + c) * 8)) * 96;
        float* pD = ws + WS_PD + ((size_t)((b * 8 + c) * 8)) * 96;
        #pragma unroll
        for (int hp = 0; hp < 8; ++hp) {
            pN[hp * 96 + fid] = num[hp] + red[fid * 17 + hp];
            pD[hp * 96 + fid] = den[hp] + red[fid * 17 + 8 + hp];
        }
    }

    // ---- Epilogue (b==0 only): ob2 partial slice c over 48 (h,j) pairs ----
    if (b == 0) {
        int sub = tid >> 6, l = tid & 63;
        float acc = 0.f;
        #pragma unroll
        for (int k = 0; k < 12; ++k) {
            int hj = c * 48 + sub * 12 + k;
            int h = hj / 96, j = hj - h * 96;
            acc += ow[(size_t)(h * 2 * D_ + D_ + j) * L_ + l];
        }
        obp2[sub][l] = acc;
        __syncthreads();
        if (sub == 0)
            ws[WS_OB2P + c * 64 + l] = obp2[0][l] + obp2[1][l]
                                     + obp2[2][l] + obp2[3][l];
    }
}

// ---------------------------------------------------------------------------
// Kernel FUSE2 (64 blocks x 1024 thr, one per b, 1 block/CU, ~154 KB LDS):
// partials -> xa -> coeffs -> (a0,a1) -> piecewise-linear table IN LDS ->
// decode all 512 positions. Same algebra as the verified round-4 kab/kdec
// (identical update order -> identical numerics), but the table never
// touches global memory: no kab->kdec launch gap, no 6.4 MB table write,
// no 25 MB cross-XCD table reads.
//
// out(y,d) = R0(k,d) + y*R1(k,d),  k = #{t_j < y},  t_j = -a0_j/a1_j,
//   u_j = |a1_j|, vt_j = -a0_j*sgn(a1_j), c0_j = |a0_j| (a1==0 case)
//   R0(0) = 0.5*(G0 + C + Vtot) + b2 ; R1(0) = 0.5*(G1 - Utot)
//   crossing t_(k): R0 -= vt*w2row ; R1 += u*w2row
// ---------------------------------------------------------------------------
__global__ __launch_bounds__(1024) void kfuse2(
    const float* __restrict__ ow, const float* __restrict__ ob,
    const float* __restrict__ w1, const float* __restrict__ b1,
    const float* __restrict__ yts, const float* __restrict__ w2,
    const float* __restrict__ b2, const float* __restrict__ ws,
    float* __restrict__ out)
{
    __shared__ float w2_s[HID_ * D_];   // 48 KB, [j][d]
    union Tail {
        float tab[129 * TS_];           // ~100 KB piecewise-linear table
        struct {                        // early scratch, dead before (i)
            float xa[768];
            float cfp[4][2][64];
            float abp[2][2][128];
        } e;
    };
    __shared__ Tail u;
    __shared__ float cf_s[2][64];
    __shared__ float ab0_s[HID_], ab1_s[HID_];
    __shared__ float t_s[HID_], u_s[HID_], vt_s[HID_], c0_s[HID_];
    __shared__ float ts_s[HID_];        // sorted thresholds
    __shared__ int   sidx_s[HID_];
    __shared__ float base0_s[96], base1_s[96];
    // static LDS total ~154.1 KB (gfx950 allows 160 KB/WG) -> 1 block/CU

    const int b = blockIdx.x, tid = threadIdx.x;

    // stage w2 (12288 floats = 3 float4/thread, coalesced; L2-hot)
    {
        const float4* src = (const float4*)w2;
        float4* dst = (float4*)w2_s;
        #pragma unroll
        for (int i = 0; i < 3; ++i) dst[tid + i * 1024] = src[tid + i * 1024];
    }

    // (a) reduce pool partials -> xa (768 items)
    if (tid < 768) {
        int hp = tid / 96, f = tid - hp * 96;
        float n = 0.f, d = 0.f;
        #pragma unroll
        for (int cc = 0; cc < 8; ++cc) {
            n += ws[WS_PN + ((size_t)((b * 8 + cc) * 8 + hp)) * 96 + f];
            d += ws[WS_PD + ((size_t)((b * 8 + cc) * 8 + hp)) * 96 + f];
        }
        u.e.xa[tid] = n / d;
    }
    __syncthreads();

    // (b) coeff GEMV: 512 items (h,p,l); each f-step reads a contiguous
    // 256 B row of ow (coalesced, L2-hot across all 64 blocks)
    if (tid < 512) {
        int h = tid >> 7, p = (tid >> 6) & 1, l = tid & 63;
        const float* xr = u.e.xa + (h * 2 + p) * 96;
        const float* owr = ow + (size_t)(h * 2 * D_) * L_ + l;
        float acc = 0.f;
        #pragma unroll 8
        for (int f = 0; f < 96; ++f)
            acc += xr[f] * owr[(size_t)f * L_];
        u.e.cfp[h][p][l] = acc;
    }
    __syncthreads();

    // (c) combine coeff partials + ob + ob2 partials
    if (tid < 128) {
        int p = tid >> 6, l = tid & 63;
        float v = u.e.cfp[0][p][l] + u.e.cfp[1][p][l] + u.e.cfp[2][p][l]
                + u.e.cfp[3][p][l] + ob[l];
        #pragma unroll
        for (int g = 0; g < 8; ++g) v += ws[WS_OB2P + g * 64 + l];
        cf_s[p][l] = v;
    }
    __syncthreads();

    // (d) a0/a1 GEMV, 256 items (s,j)
    if (tid < 256) {
        int s = tid >> 7, j = tid & 127;
        float a0 = 0.f, a1 = 0.f;
        #pragma unroll 4
        for (int li = 0; li < 32; ++li) {
            int l = s * 32 + li;
            float wv = w1[l * HID_ + j];
            a0 += cf_s[0][l] * wv;
            a1 += cf_s[1][l] * wv;
        }
        u.e.abp[s][0][j] = a0;
        u.e.abp[s][1][j] = a1;
    }
    __syncthreads();

    // (e) combine -> ab0/ab1 (last reader of u.e)
    if (tid < 128) {
        ab0_s[tid] = u.e.abp[0][0][tid] + u.e.abp[1][0][tid] + b1[tid];
    } else if (tid < 256) {
        int j = tid - 128;
        ab1_s[j] = u.e.abp[0][1][j] + u.e.abp[1][1][j];
    }
    __syncthreads();

    // (f) classify
    if (tid < 128) {
        float a0 = ab0_s[tid], a1 = ab1_s[tid];
        float t, uu, vt, c0;
        if (a1 > 0.f)      { t = -a0 / a1;  uu =  a1; vt = -a0; c0 = 0.f; }
        else if (a1 < 0.f) { t = -a0 / a1;  uu = -a1; vt =  a0; c0 = 0.f; }
        else               { t = INFINITY;  uu = 0.f; vt = 0.f; c0 = fabsf(a0); }
        t_s[tid] = t; u_s[tid] = uu; vt_s[tid] = vt; c0_s[tid] = c0;
    }
    __syncthreads();

    // (g) threshold rank sort (strict total order via index tiebreak)
    if (tid < 128) {
        float tj = t_s[tid];
        int r = 0;
        #pragma unroll 8
        for (int k = 0; k < 128; ++k) {
            float tk = t_s[k];
            r += (tk < tj) || (tk == tj && k < tid);
        }
        sidx_s[r] = tid;
    }
    __syncthreads();

    // (h) fused 5-GEMV -> base state (k=0); [128,256) writes sorted t
    if (tid < 96) {
        float g0 = 0.f, g1 = 0.f, ut = 0.f, vta = 0.f, cc2 = 0.f;
        #pragma unroll 4
        for (int j = 0; j < 128; ++j) {
            float wv = w2_s[j * 96 + tid];
            g0  += ab0_s[j] * wv;
            g1  += ab1_s[j] * wv;
            ut  += u_s[j]  * wv;
            vta += vt_s[j] * wv;
            cc2 += c0_s[j] * wv;
        }
        base0_s[tid] = 0.5f * (g0 + cc2 + vta) + b2[tid];
        base1_s[tid] = 0.5f * (g1 - ut);
    } else if (tid >= 128 && tid < 256) {
        int k = tid - 128;
        ts_s[k] = t_s[sidx_s[k]];
    }
    __syncthreads();

    // (i) prefix build -> LDS table. 96 threads (col d), serial over k
    // (129 iters x ~20 cy ~ 1 us). Bank(row k, col c) = (2k + c) mod 32.
    if (tid < 96) {
        float cur0 = base0_s[tid], cur1 = base1_s[tid];
        u.tab[tid] = cur0;
        u.tab[96 + tid] = cur1;
        #pragma unroll 4
        for (int k = 0; k < 128; ++k) {
            int j = sidx_s[k];
            float wv = w2_s[j * 96 + tid];
            cur0 -= vt_s[j] * wv;
            cur1 += u_s[j] * wv;
            u.tab[(k + 1) * TS_ + tid]      = cur0;
            u.tab[(k + 1) * TS_ + 96 + tid] = cur1;
        }
    }
    __syncthreads();

    // (j) decode: thread = (pos = tid>>1, half = tid&1 -> 48 cols).
    // Binary search (7 LDS steps) + 24 float2-pair table reads + 12 float4
    // coalesced-ish stores. Row stride TS_=194 keeps reads ~2-way max.
    {
        const int pos = tid >> 1, d0 = (tid & 1) * 48;
        const float y = yts[b * TY_ + pos];

        int lo = 0, hi = 128;
        #pragma unroll
        for (int s = 0; s < 7; ++s) {
            int mid = (lo + hi) >> 1;
            if (ts_s[mid] < y) lo = mid + 1; else hi = mid;
        }

        const float* R = u.tab + lo * TS_ + d0;
        float* op = out + ((size_t)(b * TY_ + pos)) * D_ + d0;
        #pragma unroll
        for (int q = 0; q < 12; ++q) {
            float2 r0a = *(const float2*)(R + 4 * q);
            float2 r0b = *(const float2*)(R + 4 * q + 2);
            float2 r1a = *(const float2*)(R + 96 + 4 * q);
            float2 r1b = *(const float2*)(R + 96 + 4 * q + 2);
            float4 v;
            v.x = r0a.x + y * r1a.x;
            v.y = r0a.y + y * r1a.y;
            v.z = r0b.x + y * r1b.x;
            v.w = r0b.y + y * r1b.y;
            *(float4*)(op + 4 * q) = v;
        }
    }
}

// ---------------------------------------------------------------------------
extern "C" void kernel_launch(void* const* d_in, const int* in_sizes, int n_in,
                              void* d_out, int out_size, void* d_ws, size_t ws_size,
                              hipStream_t stream)
{
    const float* timesteps = (const float*)d_in[0];
    const float* X         = (const float*)d_in[1];
    const float* M         = (const float*)d_in[2];
    const float* yts       = (const float*)d_in[3];
    const float* te_w      = (const float*)d_in[4];
    const float* te_b      = (const float*)d_in[5];
    const float* query     = (const float*)d_in[6];
    const float* q_w       = (const float*)d_in[7];
    const float* q_b       = (const float*)d_in[8];
    const float* k_w       = (const float*)d_in[9];
    const float* k_b       = (const float*)d_in[10];
    const float* ow        = (const float*)d_in[11];
    const float* ob        = (const float*)d_in[12];
    const float* w1        = (const float*)d_in[13];
    const float* b1        = (const float*)d_in[14];
    const float* w2        = (const float*)d_in[15];
    const float* b2        = (const float*)d_in[16];
    float* out = (float*)d_out;
    float* ws  = (float*)d_ws;

    kphase1<<<512, 256, 0, stream>>>(timesteps, te_w, te_b, X, M, query,
                                     q_w, q_b, k_w, k_b, ow, ws);
    kfuse2<<<B_, 1024, 0, stream>>>(ow, ob, w1, b1, yts, w2, b2, ws, out);
}

// Round 7
// 148.126 us; speedup vs baseline: 1.2550x; 1.0430x over previous
//
#include <hip/hip_runtime.h>
#include <math.h>

// Problem constants
#define B_   64
#define T_   512
#define D_   96
#define TY_  512
#define H_   4
#define DK_  32
#define E_   128
#define P_   2
#define L_   64
#define HID_ 128

// Workspace layout (float offsets)
#define WS_OB2P  1024      // 8*64 : ob2 partials (const-half of ow, 8 slices)
#define WS_PN    2048      // 64b*8c*8hp*96f = 393216 : partial numerators
#define WS_PD    395264    // 393216 : partial denominators

// LDS table row stride (floats): 194 = 192 data + 2 pad.
//   194 mod 32 = 2  -> bank(row k, col c) = (2k + c) mod 32. 194 even ->
//   float2-aligned rows. Row k: R0[96] at [0,96), R1[96] at [96,192).
#define TS_  194

// ---------------------------------------------------------------------------
// Kernel 1 (512 blocks = 8 t-chunks x 64 b, 256 thr): prep + scores + exp +
// masked pooling partials. (unchanged from round 4 — ~17 us)
// ---------------------------------------------------------------------------
__global__ __launch_bounds__(256) void kphase1(
    const float* __restrict__ tsteps, const float* __restrict__ te_w,
    const float* __restrict__ te_b,   const float* __restrict__ X,
    const float* __restrict__ M,      const float* __restrict__ query,
    const float* __restrict__ q_w,    const float* __restrict__ q_b,
    const float* __restrict__ k_w,    const float* __restrict__ k_b,
    const float* __restrict__ ow,     float* __restrict__ ws)
{
    const int bi = blockIdx.x, tid = threadIdx.x;
    const int c = bi & 7, b = bi >> 3;

    __shared__ float qm[P_ * E_];
    __shared__ float w2q_s[E_ * 8];
    __shared__ float tw_s[E_], tb_s[E_], bq_s[8];
    __shared__ float w_sB[64][8];       // [t][hp]
    __shared__ float red[96 * 17];      // stride 17: no bank conflicts
    __shared__ float obp2[4][64];

    // ---- Prologue: fused q/k weights ----
    {
        int p = tid >> 7, ep = tid & 127;
        float acc = q_b[ep];
        #pragma unroll 8
        for (int e = 0; e < E_; ++e)
            acc += query[p * E_ + e] * q_w[e * E_ + ep];
        qm[p * E_ + ep] = acc;
    }
    if (tid < E_) { tw_s[tid] = te_w[tid]; tb_s[tid] = te_b[tid]; }
    __syncthreads();
    const float rs = 0.17677669529663687f;  // 1/sqrt(32)
    #pragma unroll
    for (int i = 0; i < 4; ++i) {
        int idx = tid + i * 256;
        int e = idx >> 3, hp = idx & 7, h = hp >> 1, p = hp & 1;
        float acc = 0.f;
        #pragma unroll
        for (int dk = 0; dk < DK_; ++dk)
            acc += k_w[e * E_ + h * DK_ + dk] * qm[p * E_ + h * DK_ + dk];
        w2q_s[idx] = acc * rs;
    }
    if (tid < 8) {
        int hp = tid, h = hp >> 1, p = hp & 1;
        float acc = 0.f;
        #pragma unroll
        for (int dk = 0; dk < DK_; ++dk)
            acc += k_b[h * DK_ + dk] * qm[p * E_ + h * DK_ + dk];
        bq_s[hp] = acc * rs;
    }
    __syncthreads();

    // ---- Phase A: thread = (t in chunk, hp-pair) ----
    {
        const int t = tid & 63, hpg = tid >> 6, hp0 = hpg * 2;
        const float tv = tsteps[b * T_ + c * 64 + t];
        float a0 = 0.f, a1 = 0.f;
        #pragma unroll 4
        for (int e = 0; e < E_; ++e) {
            float v = tv * tw_s[e] + tb_s[e];
            if ((e & 3) == 0) v = __sinf(v);
            float2 w = *(const float2*)&w2q_s[e * 8 + hp0];
            a0 += v * w.x;
            a1 += v * w.y;
        }
        float e0 = __expf(a0 + bq_s[hp0]);
        float e1 = __expf(a1 + bq_s[hp0 + 1]);
        *(float2*)&w_sB[t][hp0] = make_float2(e0, e1);
    }
    __syncthreads();

    // ---- Phase B: 2 t-slices x 128 fid (96 active) ----
    const int fid = tid & 127, slice = tid >> 7;
    float num[8] = {0.f, 0.f, 0.f, 0.f, 0.f, 0.f, 0.f, 0.f};
    float den[8] = {0.f, 0.f, 0.f, 0.f, 0.f, 0.f, 0.f, 0.f};
    if (fid < 96) {
        #pragma unroll 4
        for (int i = 0; i < 32; ++i) {
            int tl = slice + 2 * i;           // wave-uniform
            size_t base = ((size_t)(b * T_ + c * 64 + tl)) * D_ + fid;
            float m = M[base], x = X[base];
            float mx = m * x;
            float4 wa = *(const float4*)&w_sB[tl][0];   // b128 broadcast
            float4 wb = *(const float4*)&w_sB[tl][4];
            float wv[8];
            *(float4*)&wv[0] = wa; *(float4*)&wv[4] = wb;
            #pragma unroll
            for (int hp = 0; hp < 8; ++hp) {
                num[hp] += wv[hp] * mx;
                den[hp] += wv[hp] * m;
            }
        }
    }
    __syncthreads();
    if (slice == 1 && fid < 96) {
        #pragma unroll
        for (int hp = 0; hp < 8; ++hp) {
            red[fid * 17 + hp]     = num[hp];
            red[fid * 17 + 8 + hp] = den[hp];
        }
    }
    __syncthreads();
    if (slice == 0 && fid < 96) {
        float* pN = ws + WS_PN + ((size_t)((b * 8 + c) * 8)) * 96;
        float* pD = ws + WS_PD + ((size_t)((b * 8 + c) * 8)) * 96;
        #pragma unroll
        for (int hp = 0; hp < 8; ++hp) {
            pN[hp * 96 + fid] = num[hp] + red[fid * 17 + hp];
            pD[hp * 96 + fid] = den[hp] + red[fid * 17 + 8 + hp];
        }
    }

    // ---- Epilogue (b==0 only): ob2 partial slice c over 48 (h,j) pairs ----
    if (b == 0) {
        int sub = tid >> 6, l = tid & 63;
        float acc = 0.f;
        #pragma unroll
        for (int k = 0; k < 12; ++k) {
            int hj = c * 48 + sub * 12 + k;
            int h = hj / 96, j = hj - h * 96;
            acc += ow[(size_t)(h * 2 * D_ + D_ + j) * L_ + l];
        }
        obp2[sub][l] = acc;
        __syncthreads();
        if (sub == 0)
            ws[WS_OB2P + c * 64 + l] = obp2[0][l] + obp2[1][l]
                                     + obp2[2][l] + obp2[3][l];
    }
}

// ---------------------------------------------------------------------------
// Kernel FUSE2 (round-7: 256 blocks = 4 per b x 1024 thr, 1 block/CU, full
// chip): each block REDUNDANTLY computes partials -> xa -> coeffs -> (a0,a1)
// -> piecewise-linear table in LDS (deterministic -> all 4 replicas agree
// bit-exactly), then decodes only its 128-position quarter with all 1024
// threads (8 threads/pos). This 4x-splits the decode LDS reads and the
// 12.6 MB output store (previously sourced from just 64 CUs -> store tail),
// at the cost of redundant table builds, which run in parallel on idle CUs.
//
// out(y,d) = R0(k,d) + y*R1(k,d),  k = #{t_j < y},  t_j = -a0_j/a1_j,
//   u_j = |a1_j|, vt_j = -a0_j*sgn(a1_j), c0_j = |a0_j| (a1==0 case)
//   R0(0) = 0.5*(G0 + C + Vtot) + b2 ; R1(0) = 0.5*(G1 - Utot)
//   crossing t_(k): R0 -= vt*w2row ; R1 += u*w2row
// ---------------------------------------------------------------------------
__global__ __launch_bounds__(1024) void kfuse2(
    const float* __restrict__ ow, const float* __restrict__ ob,
    const float* __restrict__ w1, const float* __restrict__ b1,
    const float* __restrict__ yts, const float* __restrict__ w2,
    const float* __restrict__ b2, const float* __restrict__ ws,
    float* __restrict__ out)
{
    __shared__ float w2_s[HID_ * D_];   // 48 KB, [j][d]
    union Tail {
        float tab[129 * TS_];           // ~100 KB piecewise-linear table
        struct {                        // early scratch, dead before (i)
            float xa[768];
            float cfp[4][2][64];
            float abp[2][2][128];
        } e;
    };
    __shared__ Tail u;
    __shared__ float cf_s[2][64];
    __shared__ float ab0_s[HID_], ab1_s[HID_];
    __shared__ float t_s[HID_], u_s[HID_], vt_s[HID_], c0_s[HID_];
    __shared__ float ts_s[HID_];        // sorted thresholds
    __shared__ int   sidx_s[HID_];
    __shared__ float base0_s[96], base1_s[96];
    // static LDS total ~154.1 KB -> 1 block/CU; 256 blocks fill the chip

    const int bi = blockIdx.x, tid = threadIdx.x;
    const int b = bi >> 2, bq = bi & 3;   // batch, position-quarter

    // stage w2 (12288 floats = 3 float4/thread, coalesced; L2-hot)
    {
        const float4* src = (const float4*)w2;
        float4* dst = (float4*)w2_s;
        #pragma unroll
        for (int i = 0; i < 3; ++i) dst[tid + i * 1024] = src[tid + i * 1024];
    }

    // (a) reduce pool partials -> xa (768 items)
    if (tid < 768) {
        int hp = tid / 96, f = tid - hp * 96;
        float n = 0.f, d = 0.f;
        #pragma unroll
        for (int cc = 0; cc < 8; ++cc) {
            n += ws[WS_PN + ((size_t)((b * 8 + cc) * 8 + hp)) * 96 + f];
            d += ws[WS_PD + ((size_t)((b * 8 + cc) * 8 + hp)) * 96 + f];
        }
        u.e.xa[tid] = n / d;
    }
    __syncthreads();

    // (b) coeff GEMV: 512 items (h,p,l); each f-step reads a contiguous
    // 256 B row of ow (coalesced, L2-hot across all blocks)
    if (tid < 512) {
        int h = tid >> 7, p = (tid >> 6) & 1, l = tid & 63;
        const float* xr = u.e.xa + (h * 2 + p) * 96;
        const float* owr = ow + (size_t)(h * 2 * D_) * L_ + l;
        float acc = 0.f;
        #pragma unroll 8
        for (int f = 0; f < 96; ++f)
            acc += xr[f] * owr[(size_t)f * L_];
        u.e.cfp[h][p][l] = acc;
    }
    __syncthreads();

    // (c) combine coeff partials + ob + ob2 partials
    if (tid < 128) {
        int p = tid >> 6, l = tid & 63;
        float v = u.e.cfp[0][p][l] + u.e.cfp[1][p][l] + u.e.cfp[2][p][l]
                + u.e.cfp[3][p][l] + ob[l];
        #pragma unroll
        for (int g = 0; g < 8; ++g) v += ws[WS_OB2P + g * 64 + l];
        cf_s[p][l] = v;
    }
    __syncthreads();

    // (d) a0/a1 GEMV, 256 items (s,j)
    if (tid < 256) {
        int s = tid >> 7, j = tid & 127;
        float a0 = 0.f, a1 = 0.f;
        #pragma unroll 4
        for (int li = 0; li < 32; ++li) {
            int l = s * 32 + li;
            float wv = w1[l * HID_ + j];
            a0 += cf_s[0][l] * wv;
            a1 += cf_s[1][l] * wv;
        }
        u.e.abp[s][0][j] = a0;
        u.e.abp[s][1][j] = a1;
    }
    __syncthreads();

    // (e) combine -> ab0/ab1 (last reader of u.e)
    if (tid < 128) {
        ab0_s[tid] = u.e.abp[0][0][tid] + u.e.abp[1][0][tid] + b1[tid];
    } else if (tid < 256) {
        int j = tid - 128;
        ab1_s[j] = u.e.abp[0][1][j] + u.e.abp[1][1][j];
    }
    __syncthreads();

    // (f) classify
    if (tid < 128) {
        float a0 = ab0_s[tid], a1 = ab1_s[tid];
        float t, uu, vt, c0;
        if (a1 > 0.f)      { t = -a0 / a1;  uu =  a1; vt = -a0; c0 = 0.f; }
        else if (a1 < 0.f) { t = -a0 / a1;  uu = -a1; vt =  a0; c0 = 0.f; }
        else               { t = INFINITY;  uu = 0.f; vt = 0.f; c0 = fabsf(a0); }
        t_s[tid] = t; u_s[tid] = uu; vt_s[tid] = vt; c0_s[tid] = c0;
    }
    __syncthreads();

    // (g) threshold rank sort (strict total order via index tiebreak)
    if (tid < 128) {
        float tj = t_s[tid];
        int r = 0;
        #pragma unroll 8
        for (int k = 0; k < 128; ++k) {
            float tk = t_s[k];
            r += (tk < tj) || (tk == tj && k < tid);
        }
        sidx_s[r] = tid;
    }
    __syncthreads();

    // (h) fused 5-GEMV -> base state (k=0); [128,256) writes sorted t
    if (tid < 96) {
        float g0 = 0.f, g1 = 0.f, ut = 0.f, vta = 0.f, cc2 = 0.f;
        #pragma unroll 4
        for (int j = 0; j < 128; ++j) {
            float wv = w2_s[j * 96 + tid];
            g0  += ab0_s[j] * wv;
            g1  += ab1_s[j] * wv;
            ut  += u_s[j]  * wv;
            vta += vt_s[j] * wv;
            cc2 += c0_s[j] * wv;
        }
        base0_s[tid] = 0.5f * (g0 + cc2 + vta) + b2[tid];
        base1_s[tid] = 0.5f * (g1 - ut);
    } else if (tid >= 128 && tid < 256) {
        int k = tid - 128;
        ts_s[k] = t_s[sidx_s[k]];
    }
    __syncthreads();

    // (i) prefix build -> LDS table. 96 threads (col d), serial over k.
    if (tid < 96) {
        float cur0 = base0_s[tid], cur1 = base1_s[tid];
        u.tab[tid] = cur0;
        u.tab[96 + tid] = cur1;
        #pragma unroll 4
        for (int k = 0; k < 128; ++k) {
            int j = sidx_s[k];
            float wv = w2_s[j * 96 + tid];
            cur0 -= vt_s[j] * wv;
            cur1 += u_s[j] * wv;
            u.tab[(k + 1) * TS_ + tid]      = cur0;
            u.tab[(k + 1) * TS_ + 96 + tid] = cur1;
        }
    }
    __syncthreads();

    // (j) decode this block's quarter: 128 positions x 8 threads each.
    // thread = (pos = tid>>3, oct = tid&7 -> 12 cols). All 1024 threads
    // active; per thread: 7-step binary search + 12 float2 table reads +
    // 3 float4 global stores (row base 384 B-aligned, oct*48 B offset).
    {
        const int pos = tid >> 3, oct = tid & 7;
        const int gpos = bq * 128 + pos;
        const float y = yts[b * TY_ + gpos];

        int lo = 0, hi = 128;
        #pragma unroll
        for (int s = 0; s < 7; ++s) {
            int mid = (lo + hi) >> 1;
            if (ts_s[mid] < y) lo = mid + 1; else hi = mid;
        }

        const float* R = u.tab + lo * TS_ + oct * 12;
        float vout[12];
        #pragma unroll
        for (int q = 0; q < 6; ++q) {
            float2 r0 = *(const float2*)(R + 2 * q);
            float2 r1 = *(const float2*)(R + 96 + 2 * q);
            vout[2 * q]     = r0.x + y * r1.x;
            vout[2 * q + 1] = r0.y + y * r1.y;
        }
        float* op = out + ((size_t)(b * TY_ + gpos)) * D_ + oct * 12;
        #pragma unroll
        for (int s = 0; s < 3; ++s)
            *(float4*)(op + 4 * s) = make_float4(vout[4 * s], vout[4 * s + 1],
                                                 vout[4 * s + 2], vout[4 * s + 3]);
    }
}

// ---------------------------------------------------------------------------
extern "C" void kernel_launch(void* const* d_in, const int* in_sizes, int n_in,
                              void* d_out, int out_size, void* d_ws, size_t ws_size,
                              hipStream_t stream)
{
    const float* timesteps = (const float*)d_in[0];
    const float* X         = (const float*)d_in[1];
    const float* M         = (const float*)d_in[2];
    const float* yts       = (const float*)d_in[3];
    const float* te_w      = (const float*)d_in[4];
    const float* te_b      = (const float*)d_in[5];
    const float* query     = (const float*)d_in[6];
    const float* q_w       = (const float*)d_in[7];
    const float* q_b       = (const float*)d_in[8];
    const float* k_w       = (const float*)d_in[9];
    const float* k_b       = (const float*)d_in[10];
    const float* ow        = (const float*)d_in[11];
    const float* ob        = (const float*)d_in[12];
    const float* w1        = (const float*)d_in[13];
    const float* b1        = (const float*)d_in[14];
    const float* w2        = (const float*)d_in[15];
    const float* b2        = (const float*)d_in[16];
    float* out = (float*)d_out;
    float* ws  = (float*)d_ws;

    kphase1<<<512, 256, 0, stream>>>(timesteps, te_w, te_b, X, M, query,
                                     q_w, q_b, k_w, k_b, ow, ws);
    kfuse2<<<4 * B_, 1024, 0, stream>>>(ow, ob, w1, b1, yts, w2, b2, ws, out);
}